// Round 3
// baseline (159.223 us; speedup 1.0000x reference)
//
#include <hip/hip_runtime.h>
#include <math.h>

// R3: f16 feature tables in d_ws (3 MB -> L2-resident). Inner product via
// v_dot2_f32_f16 (pkmul + 3x fdot2 per h2 chunk: 64 VALU/pair/lane vs 144).
// W kept as f16 pairs in registers. idx loaded as int2. Single fused cvt
// kernel. 8 lanes/edge, 2 edges per group-iteration.

typedef _Float16 h2 __attribute__((ext_vector_type(2)));
union U16 { uint4 u; h2 h[4]; };
union HU { uint u; h2 h; };

// ---------- fused conversion kernel: both tables f32 -> f16 ------------------
__global__ __launch_bounds__(256) void cvt_f16_fused_kernel(
    const float4* __restrict__ srcA, int nA4,   // ufeats
    const float4* __restrict__ srcB, int nB4,   // ifeats
    uint2* __restrict__ dst)                    // uhalf ++ ihalf contiguous
{
    int i = blockIdx.x * blockDim.x + threadIdx.x;
    if (i >= nA4 + nB4) return;
    float4 f = (i < nA4) ? srcA[i] : srcB[i - nA4];
    HU a, b;
    a.h = h2{(_Float16)f.x, (_Float16)f.y};
    b.h = h2{(_Float16)f.z, (_Float16)f.w};
    dst[i] = make_uint2(a.u, b.u);
}

// ---------- main edge kernel -------------------------------------------------
__global__ __launch_bounds__(256) void zinb_edge_dot2_kernel(
    const _Float16* __restrict__ uhalf,   // [n_cells, 128]
    const _Float16* __restrict__ ihalf,   // [n_genes, 128]
    const float* __restrict__ ge_factor,
    const float* __restrict__ sz_factor,
    const float* __restrict__ W_mean, const float* __restrict__ b_mean,
    const float* __restrict__ W_disp, const float* __restrict__ b_disp,
    const float* __restrict__ W_pi,   const float* __restrict__ b_pi,
    const int* __restrict__ src_idx,
    const int* __restrict__ dst_idx,
    float* __restrict__ out,              // [3E]: mu | disp | pi
    int E)
{
    const int r = threadIdx.x & 7;
    const int slot = (blockIdx.x * blockDim.x + threadIdx.x) >> 3;
    const int n_slots = (gridDim.x * blockDim.x) >> 3;

    // W slices as f16 pairs. Lane r owns elems [r*8, r*8+8) and [64+r*8, ...).
    h2 wm[8], wd[8], wp[8];
#pragma unroll
    for (int c = 0; c < 2; ++c)
#pragma unroll
        for (int j = 0; j < 4; ++j) {
            int k = c * 64 + r * 8 + 2 * j;
            wm[c * 4 + j] = h2{(_Float16)W_mean[k], (_Float16)W_mean[k + 1]};
            wd[c * 4 + j] = h2{(_Float16)W_disp[k], (_Float16)W_disp[k + 1]};
            wp[c * 4 + j] = h2{(_Float16)W_pi[k],   (_Float16)W_pi[k + 1]};
        }
    const float bm = b_mean[0], bd = b_disp[0], bp = b_pi[0];

    const int npairs = E >> 1;
    const int2* src2 = (const int2*)src_idx;
    const int2* dst2 = (const int2*)dst_idx;

    for (int p = slot; p < npairs; p += n_slots) {
        const int e0 = 2 * p;
        const int2 ss = src2[p];
        const int2 gg = dst2[p];

        const uint4* u0p = (const uint4*)(uhalf + (size_t)ss.x * 128);
        const uint4* v0p = (const uint4*)(ihalf + (size_t)gg.x * 128);
        const uint4* u1p = (const uint4*)(uhalf + (size_t)ss.y * 128);
        const uint4* v1p = (const uint4*)(ihalf + (size_t)gg.y * 128);

        U16 ua, ub, va, vb, uc, ud, vc, vd2;
        ua.u = u0p[r];     va.u = v0p[r];
        ub.u = u0p[r + 8]; vb.u = v0p[r + 8];
        uc.u = u1p[r];     vc.u = v1p[r];
        ud.u = u1p[r + 8]; vd2.u = v1p[r + 8];

        float am0 = 0.f, ad0 = 0.f, ap0 = 0.f;
        float am1 = 0.f, ad1 = 0.f, ap1 = 0.f;
#pragma unroll
        for (int j = 0; j < 4; ++j) {
            h2 pa = ua.h[j] * va.h[j];
            am0 = __builtin_amdgcn_fdot2(pa, wm[j], am0, false);
            ad0 = __builtin_amdgcn_fdot2(pa, wd[j], ad0, false);
            ap0 = __builtin_amdgcn_fdot2(pa, wp[j], ap0, false);
            h2 pb = ub.h[j] * vb.h[j];
            am0 = __builtin_amdgcn_fdot2(pb, wm[4 + j], am0, false);
            ad0 = __builtin_amdgcn_fdot2(pb, wd[4 + j], ad0, false);
            ap0 = __builtin_amdgcn_fdot2(pb, wp[4 + j], ap0, false);
            h2 pc = uc.h[j] * vc.h[j];
            am1 = __builtin_amdgcn_fdot2(pc, wm[j], am1, false);
            ad1 = __builtin_amdgcn_fdot2(pc, wd[j], ad1, false);
            ap1 = __builtin_amdgcn_fdot2(pc, wp[j], ap1, false);
            h2 pd = ud.h[j] * vd2.h[j];
            am1 = __builtin_amdgcn_fdot2(pd, wm[4 + j], am1, false);
            ad1 = __builtin_amdgcn_fdot2(pd, wd[4 + j], ad1, false);
            ap1 = __builtin_amdgcn_fdot2(pd, wp[4 + j], ap1, false);
        }

#pragma unroll
        for (int off = 1; off < 8; off <<= 1) {
            am0 += __shfl_xor(am0, off); ad0 += __shfl_xor(ad0, off); ap0 += __shfl_xor(ap0, off);
            am1 += __shfl_xor(am1, off); ad1 += __shfl_xor(ad1, off); ap1 += __shfl_xor(ap1, off);
        }

        if ((r & 3) == 0) {
            const int  e = (r == 0) ? e0 : e0 + 1;
            const int  s = (r == 0) ? ss.x : ss.y;
            const int  g = (r == 0) ? gg.x : gg.y;
            const float am = (r == 0) ? am0 : am1;
            const float ad = (r == 0) ? ad0 : ad1;
            const float ap = (r == 0) ? ap0 : ap1;

            const float gef = ge_factor[g];
            const float szf = sz_factor[s];

            const float mu_ = 1.f / (1.f + __expf(-(am + bm)));
            const float pi  = 1.f / (1.f + __expf(-(ap + bp)));
            const float xd  = gef * (ad + bd);
            const float sp  = fmaxf(xd, 0.f) + __logf(1.f + __expf(-fabsf(xd)));
            const float disp = fminf(fmaxf(sp, 1e-4f), 1e4f);
            const float mu = szf * fminf(fmaxf(__expf(gef * mu_) - 1.f, 1e-5f), 1e6f);

            out[e]                 = mu;
            out[(size_t)E + e]     = disp;
            out[(size_t)2 * E + e] = pi;
        }
    }

    // Odd-E tail: process edge E-1 with group 0 (8 lanes, single edge).
    if ((E & 1) && slot == 0) {
        const int e = E - 1;
        const int s = src_idx[e];
        const int g = dst_idx[e];
        const uint4* up = (const uint4*)(uhalf + (size_t)s * 128);
        const uint4* vp = (const uint4*)(ihalf + (size_t)g * 128);
        U16 ua, ub, va, vb;
        ua.u = up[r]; va.u = vp[r]; ub.u = up[r + 8]; vb.u = vp[r + 8];
        float am = 0.f, ad = 0.f, ap = 0.f;
#pragma unroll
        for (int j = 0; j < 4; ++j) {
            h2 pa = ua.h[j] * va.h[j];
            am = __builtin_amdgcn_fdot2(pa, wm[j], am, false);
            ad = __builtin_amdgcn_fdot2(pa, wd[j], ad, false);
            ap = __builtin_amdgcn_fdot2(pa, wp[j], ap, false);
            h2 pb = ub.h[j] * vb.h[j];
            am = __builtin_amdgcn_fdot2(pb, wm[4 + j], am, false);
            ad = __builtin_amdgcn_fdot2(pb, wd[4 + j], ad, false);
            ap = __builtin_amdgcn_fdot2(pb, wp[4 + j], ap, false);
        }
#pragma unroll
        for (int off = 1; off < 8; off <<= 1) {
            am += __shfl_xor(am, off); ad += __shfl_xor(ad, off); ap += __shfl_xor(ap, off);
        }
        if (r == 0) {
            const float gef = ge_factor[g];
            const float szf = sz_factor[s];
            const float mu_ = 1.f / (1.f + __expf(-(am + bm)));
            const float pi  = 1.f / (1.f + __expf(-(ap + bp)));
            const float xd  = gef * (ad + bd);
            const float sp  = fmaxf(xd, 0.f) + __logf(1.f + __expf(-fabsf(xd)));
            const float disp = fminf(fmaxf(sp, 1e-4f), 1e4f);
            const float mu = szf * fminf(fmaxf(__expf(gef * mu_) - 1.f, 1e-5f), 1e6f);
            out[e] = mu; out[(size_t)E + e] = disp; out[(size_t)2 * E + e] = pi;
        }
    }
}

// ---------- fallback: pure-f32 kernel (ws too small) -------------------------
__global__ __launch_bounds__(256) void zinb_edge_f32_kernel(
    const float* __restrict__ ufeats, const float* __restrict__ ifeats,
    const float* __restrict__ ge_factor, const float* __restrict__ sz_factor,
    const float* __restrict__ W_mean, const float* __restrict__ b_mean,
    const float* __restrict__ W_disp, const float* __restrict__ b_disp,
    const float* __restrict__ W_pi,   const float* __restrict__ b_pi,
    const int* __restrict__ src_idx, const int* __restrict__ dst_idx,
    float* __restrict__ out, int E)
{
    const int r = threadIdx.x & 7;
    const int slot = (blockIdx.x * blockDim.x + threadIdx.x) >> 3;
    const int n_slots = (gridDim.x * blockDim.x) >> 3;

    float4 wm[4], wd[4], wp[4];
    {
        const float4* wm4 = (const float4*)W_mean + r;
        const float4* wd4 = (const float4*)W_disp + r;
        const float4* wp4 = (const float4*)W_pi   + r;
#pragma unroll
        for (int c = 0; c < 4; ++c) { wm[c] = wm4[c*8]; wd[c] = wd4[c*8]; wp[c] = wp4[c*8]; }
    }
    const float bm = b_mean[0], bd = b_disp[0], bp = b_pi[0];

    for (int e = slot; e < E; e += n_slots) {
        const int s = src_idx[e];
        const int g = dst_idx[e];
        const float4* u4 = (const float4*)(ufeats + (size_t)s * 128) + r;
        const float4* v4 = (const float4*)(ifeats + (size_t)g * 128) + r;
        float am = 0.f, ad = 0.f, ap = 0.f;
#pragma unroll
        for (int c = 0; c < 4; ++c) {
            float4 u = u4[c*8]; float4 v = v4[c*8];
            float px = u.x*v.x, py = u.y*v.y, pz = u.z*v.z, pw = u.w*v.w;
            am = fmaf(px, wm[c].x, am); am = fmaf(py, wm[c].y, am);
            am = fmaf(pz, wm[c].z, am); am = fmaf(pw, wm[c].w, am);
            ad = fmaf(px, wd[c].x, ad); ad = fmaf(py, wd[c].y, ad);
            ad = fmaf(pz, wd[c].z, ad); ad = fmaf(pw, wd[c].w, ad);
            ap = fmaf(px, wp[c].x, ap); ap = fmaf(py, wp[c].y, ap);
            ap = fmaf(pz, wp[c].z, ap); ap = fmaf(pw, wp[c].w, ap);
        }
#pragma unroll
        for (int off = 1; off < 8; off <<= 1) {
            am += __shfl_xor(am, off); ad += __shfl_xor(ad, off); ap += __shfl_xor(ap, off);
        }
        if (r == 0) {
            const float gef = ge_factor[g];
            const float szf = sz_factor[s];
            const float mu_ = 1.f / (1.f + __expf(-(am + bm)));
            const float pi  = 1.f / (1.f + __expf(-(ap + bp)));
            const float xd  = gef * (ad + bd);
            const float sp  = fmaxf(xd, 0.f) + __logf(1.f + __expf(-fabsf(xd)));
            const float disp = fminf(fmaxf(sp, 1e-4f), 1e4f);
            const float mu = szf * fminf(fmaxf(__expf(gef * mu_) - 1.f, 1e-5f), 1e6f);
            out[e] = mu; out[(size_t)E + e] = disp; out[(size_t)2*E + e] = pi;
        }
    }
}

extern "C" void kernel_launch(void* const* d_in, const int* in_sizes, int n_in,
                              void* d_out, int out_size, void* d_ws, size_t ws_size,
                              hipStream_t stream) {
    const float* ufeats    = (const float*)d_in[0];
    const float* ifeats    = (const float*)d_in[1];
    const float* ge_factor = (const float*)d_in[2];
    const float* sz_factor = (const float*)d_in[3];
    const float* W_mean    = (const float*)d_in[4];
    const float* b_mean    = (const float*)d_in[5];
    const float* W_disp    = (const float*)d_in[6];
    const float* b_disp    = (const float*)d_in[7];
    const float* W_pi      = (const float*)d_in[8];
    const float* b_pi      = (const float*)d_in[9];
    const int*   src_idx   = (const int*)d_in[10];
    const int*   dst_idx   = (const int*)d_in[11];
    float* out = (float*)d_out;

    const int E       = in_sizes[10];
    const int n_cells = in_sizes[0] / 128;
    const int n_genes = in_sizes[1] / 128;

    const size_t u_elems = (size_t)n_cells * 128;
    const size_t i_elems = (size_t)n_genes * 128;
    const size_t ws_needed = (u_elems + i_elems) * sizeof(_Float16);

    if (ws_size >= ws_needed) {
        _Float16* uhalf = (_Float16*)d_ws;
        _Float16* ihalf = uhalf + u_elems;

        const int un4 = (int)(u_elems / 4);
        const int in4 = (int)(i_elems / 4);
        const int n4  = un4 + in4;
        hipLaunchKernelGGL(cvt_f16_fused_kernel, dim3((n4 + 255) / 256), dim3(256), 0, stream,
                           (const float4*)ufeats, un4, (const float4*)ifeats, in4,
                           (uint2*)d_ws);

        hipLaunchKernelGGL(zinb_edge_dot2_kernel, dim3(2048), dim3(256), 0, stream,
                           uhalf, ihalf, ge_factor, sz_factor,
                           W_mean, b_mean, W_disp, b_disp, W_pi, b_pi,
                           src_idx, dst_idx, out, E);
    } else {
        hipLaunchKernelGGL(zinb_edge_f32_kernel, dim3(2048), dim3(256), 0, stream,
                           ufeats, ifeats, ge_factor, sz_factor,
                           W_mean, b_mean, W_disp, b_disp, W_pi, b_pi,
                           src_idx, dst_idx, out, E);
    }
}